// Round 8
// baseline (159.054 us; speedup 1.0000x reference)
//
#include <hip/hip_runtime.h>
#include <hip/hip_bf16.h>
#include <stdint.h>

// x[2,8192,2048] f32; weight[2048,2048] fp8e4m3fn pushed as f32 values;
// scales pushed as f32 scalars (established rounds 0-7). out[2,8192,2048] f32.
#define M_DIM 16384
#define N_DIM 2048
#define K_DIM 2048

typedef float    f32x4 __attribute__((ext_vector_type(4)));
typedef uint32_t u32x4 __attribute__((ext_vector_type(4)));
typedef int      i32x8 __attribute__((ext_vector_type(8)));

#define SCALE_ONE 0x7F7F7F7F   // e8m0 exp 127 -> 1.0 in all byte lanes

__device__ inline uint32_t quant4(float4 v, float rs) {
    float q0 = fminf(fmaxf(v.x * rs, -448.f), 448.f);
    float q1 = fminf(fmaxf(v.y * rs, -448.f), 448.f);
    float q2 = fminf(fmaxf(v.z * rs, -448.f), 448.f);
    float q3 = fminf(fmaxf(v.w * rs, -448.f), 448.f);
    int p = __builtin_amdgcn_cvt_pk_fp8_f32(q0, q1, 0, false);  // bytes 0,1
    p     = __builtin_amdgcn_cvt_pk_fp8_f32(q2, q3, p, true);   // bytes 2,3
    return (uint32_t)p;
}

// ---------------------------------------------------------------------------
// Pass 1 (merged): quantize X (scaled) and convert W (exact) -> fp8 row-major.
// Blocks 0..2047: X (16 u32/thread). Blocks 2048..3071: W (4 u32/thread).
// ---------------------------------------------------------------------------
__global__ __launch_bounds__(256) void quant_xw_kernel(
    const float* __restrict__ x, const float* __restrict__ w,
    const float* __restrict__ s_ptr,
    uint32_t* __restrict__ xq, uint32_t* __restrict__ wq)
{
    if (blockIdx.x < 2048) {
        const float rs = 1.0f / s_ptr[0];
        const float4* xf4 = (const float4*)x;
        const int base = blockIdx.x * 4096 + threadIdx.x;
#pragma unroll
        for (int k = 0; k < 16; ++k) {
            const int i = base + k * 256;
            xq[i] = quant4(xf4[i], rs);
        }
    } else {
        const float4* wf4 = (const float4*)w;
        const int base = (blockIdx.x - 2048) * 1024 + threadIdx.x;
#pragma unroll
        for (int k = 0; k < 4; ++k) {
            const int i = base + k * 256;
            wq[i] = quant4(wf4[i], 1.0f);   // e4m3-representable: exact
        }
    }
}

// ---------------------------------------------------------------------------
// Pass 2: MX-fp8 GEMM, 256x128 tile, BK=128, ring-3 LDS (counted vmcnt, T3/T4).
// LDS slot (48 KB): A regions [iss 0..31]*1024, B at +32768 [pb 0..15]*1024.
// Region content: lane*16 holds operand[bandrow + (lane&15)][kb=(lane>>4)*32
// + jj*16 ..+15] -> every ds_read is base + lane*16 (bank-uniform, no
// conflicts), and staging gathers straight from row-major fp8 (per-lane
// global addresses; LDS written linearly by global_load_lds).
// ---------------------------------------------------------------------------
#define G_BM 256
#define G_BN 128
#define G_NT 16                 // K / 128
#define G_GM (M_DIM / G_BM)     // 64
#define G_GN (N_DIM / G_BN)     // 16
#define SLOT 49152              // 32 KB A + 16 KB B

extern __shared__ uint8_t smem[];

__global__ __launch_bounds__(512, 1) void gemm_mx_256(
    const uint8_t* __restrict__ Aq,   // [M][K] fp8 row-major
    const uint8_t* __restrict__ Wq,   // [N][K] fp8 row-major
    const float* __restrict__ wscale,
    const float* __restrict__ iscale,
    float* __restrict__ out)
{
    const int tid  = threadIdx.x;
    const int lane = tid & 63;
    const int wid  = tid >> 6;

    // Bijective XCD swizzle (1024 % 8 == 0); consecutive wg share bm.
    const int bid = blockIdx.x;
    const int wg  = (bid & 7) * (G_GM * G_GN / 8) + (bid >> 3);
    const int bm  = wg >> 4;
    const int bn  = wg & 15;
    const int rowBase = bm * G_BM;
    const int colBase = bn * G_BN;

    // Materialize scales NOW so their loads drain before staging begins
    // (keeps the counted-vmcnt bookkeeping exact).
    const float scv = wscale[0] * iscale[0];
    asm volatile("" :: "v"(scv));

    // Per-wave staging descriptors: 6 issues (A: iss 0..31, B: 32..47).
    const uint8_t* gsrc[6];
    int ldsoff[6];
#pragma unroll
    for (int j = 0; j < 6; ++j) {
        const int iss = wid + j * 8;
        const int jj  = iss & 1;
        const int col = (lane >> 4) * 32 + jj * 16;
        int row; const uint8_t* base; int lo;
        if (iss < 32) {   // A region (wr4 = iss>>3, m = (iss>>1)&3, jj)
            row  = rowBase + (iss >> 3) * 64 + ((iss >> 1) & 3) * 16 + (lane & 15);
            base = Aq;  lo = iss * 1024;
        } else {          // B region (wc2 = pb>>3, n = (pb>>1)&3, jj)
            const int pb = iss - 32;
            row  = colBase + (pb >> 3) * 64 + ((pb >> 1) & 3) * 16 + (lane & 15);
            base = Wq;  lo = 32768 + pb * 1024;
        }
        gsrc[j]   = base + (size_t)row * K_DIM + col;
        ldsoff[j] = lo;
    }

    auto stage = [&](int slot, int tt) {
        const size_t koff = (size_t)tt * 128;
        uint8_t* sb = smem + slot * SLOT;
#pragma unroll
        for (int j = 0; j < 6; ++j)
            __builtin_amdgcn_global_load_lds(
                (const __attribute__((address_space(1))) void*)(gsrc[j] + koff),
                (__attribute__((address_space(3))) void*)(sb + ldsoff[j]),
                16, 0, 0);
    };

    const int aBase = (wid >> 1) * 8192;           // wr4 * 4 regions * 2048
    const int bBase = 32768 + (wid & 1) * 8192;    // wc2 * 4 regions * 2048
    const int l16   = lane * 16;

    f32x4 acc[4][4] = {};

    // Prologue: fill ring with tiles 0,1,2; wait for tile 0 only.
    stage(0, 0); stage(1, 1); stage(2, 2);
    asm volatile("s_waitcnt vmcnt(12)" ::: "memory");
    __builtin_amdgcn_s_barrier();
    __builtin_amdgcn_sched_barrier(0);

    for (int t = 0; t < G_NT; ++t) {
        const int slot = t % 3;
        const uint8_t* sb = smem + slot * SLOT;

        // Fragment reads: 16x ds_read_b128, each uniform_base + lane*16.
        u32x4 aLo[4], aHi[4], bLo[4], bHi[4];
#pragma unroll
        for (int m = 0; m < 4; ++m) {
            aLo[m] = *(const u32x4*)(sb + aBase + m * 2048 + l16);
            aHi[m] = *(const u32x4*)(sb + aBase + m * 2048 + 1024 + l16);
        }
#pragma unroll
        for (int n = 0; n < 4; ++n) {
            bLo[n] = *(const u32x4*)(sb + bBase + n * 2048 + l16);
            bHi[n] = *(const u32x4*)(sb + bBase + n * 2048 + 1024 + l16);
        }
        __builtin_amdgcn_sched_barrier(0);
        asm volatile("s_waitcnt lgkmcnt(0)" ::: "memory");  // my reads done
        __builtin_amdgcn_s_barrier();                        // everyone's done
        __builtin_amdgcn_sched_barrier(0);

        // Overwrite the just-consumed slot with tile t+3 (dummy re-stage of
        // tile 15 at the tail keeps vmcnt counts uniform; never read).
        stage(slot, (t + 3 > G_NT - 1) ? G_NT - 1 : t + 3);
        __builtin_amdgcn_sched_barrier(0);

        __builtin_amdgcn_s_setprio(1);
#pragma unroll
        for (int m = 0; m < 4; ++m) {
            const i32x8 av = {(int)aLo[m].x, (int)aLo[m].y, (int)aLo[m].z, (int)aLo[m].w,
                              (int)aHi[m].x, (int)aHi[m].y, (int)aHi[m].z, (int)aHi[m].w};
#pragma unroll
            for (int n = 0; n < 4; ++n) {
                const i32x8 bv = {(int)bLo[n].x, (int)bLo[n].y, (int)bLo[n].z, (int)bLo[n].w,
                                  (int)bHi[n].x, (int)bHi[n].y, (int)bHi[n].z, (int)bHi[n].w};
                acc[m][n] = __builtin_amdgcn_mfma_scale_f32_16x16x128_f8f6f4(
                    av, bv, acc[m][n], 0, 0, 0, SCALE_ONE, 0, SCALE_ONE);
            }
        }
        __builtin_amdgcn_s_setprio(0);
        __builtin_amdgcn_sched_barrier(0);

        // Counted wait: in flight = t+1 (6), t+2 (6), t+3 (6) -> drain to 12
        // completes tile t+1 (oldest). Loads for t+2/t+3 stay in flight.
        asm volatile("s_waitcnt vmcnt(12)" ::: "memory");
        __builtin_amdgcn_s_barrier();
        __builtin_amdgcn_sched_barrier(0);
    }

    // Epilogue. C/D layout: col = lane&15, row = (lane>>4)*4 + reg (validated).
    const int wrow = (wid >> 1) * 64;
    const int wcol = (wid & 1) * 64;
    const int crow = (lane >> 4) << 2;
    const int ccol = lane & 15;
#pragma unroll
    for (int m = 0; m < 4; ++m) {
#pragma unroll
        for (int n = 0; n < 4; ++n) {
            const size_t base = (size_t)(rowBase + wrow + m * 16 + crow) * N_DIM
                              + (colBase + wcol + n * 16 + ccol);
#pragma unroll
            for (int r = 0; r < 4; ++r)
                out[base + (size_t)r * N_DIM] = acc[m][n][r] * scv;
        }
    }
}

// ---------------------------------------------------------------------------
// Fallback (ws too small / attribute failure): proven round-4 fused kernel.
// ---------------------------------------------------------------------------
__global__ __launch_bounds__(256) void fused_fp8_gemm(
    const float* __restrict__ X, const float* __restrict__ Wf,
    const float* __restrict__ wscale, const float* __restrict__ iscale,
    float* __restrict__ out)
{
    __shared__ uint8_t smA[2][128 * 64];
    __shared__ uint8_t smB[2][128 * 64];

    const int tid  = threadIdx.x;
    const int lane = tid & 63;
    const int wid  = tid >> 6;

    const float s  = iscale[0];
    const float rs = 1.0f / s;
    const float sc = wscale[0] * s;

    const int bid = blockIdx.x;
    const int wg  = (bid & 7) * 256 + (bid >> 3);
    const int bm  = wg >> 4;
    const int bn  = wg & 15;
    const int rowBase = bm * 128;
    const int colBase = bn * 128;
    const int wrow = (wid >> 1) * 64;
    const int wcol = (wid & 1) * 64;
    const int ar = tid >> 1;
    const int ah = (tid & 1) * 32;

    const float* Xrow = X  + (size_t)(rowBase + ar) * K_DIM;
    const float* Wrow = Wf + (size_t)(colBase + ar) * K_DIM;

    float4 areg[8], breg[8];
    auto load_tile = [&](int kt) {
        const int k0 = kt * 64;
#pragma unroll
        for (int j = 0; j < 8; ++j) areg[j] = *(const float4*)(Xrow + k0 + ah + j * 4);
#pragma unroll
        for (int j = 0; j < 8; ++j) breg[j] = *(const float4*)(Wrow + k0 + ah + j * 4);
    };
    auto write_tile = [&](int buf) {
        uint32_t aq[8], bq[8];
#pragma unroll
        for (int j = 0; j < 8; ++j) { aq[j] = quant4(areg[j], rs); bq[j] = quant4(breg[j], 1.0f); }
        *(u32x4*)&smA[buf][ar * 64 + ah]      = *(const u32x4*)&aq[0];
        *(u32x4*)&smA[buf][ar * 64 + ah + 16] = *(const u32x4*)&aq[4];
        *(u32x4*)&smB[buf][ar * 64 + ah]      = *(const u32x4*)&bq[0];
        *(u32x4*)&smB[buf][ar * 64 + ah + 16] = *(const u32x4*)&bq[4];
    };

    f32x4 acc[4][4] = {};
    load_tile(0); write_tile(0); __syncthreads();
    for (int kt = 0; kt < 32; ++kt) {
        const int cur = kt & 1;
        if (kt + 1 < 32) load_tile(kt + 1);
        const uint8_t* pA = smA[cur];
        const uint8_t* pB = smB[cur];
        const int afr = lane & 15, koff = (lane >> 4) << 3;
#pragma unroll
        for (int kk = 0; kk < 2; ++kk) {
            long long a[4], b[4];
#pragma unroll
            for (int m = 0; m < 4; ++m)
                a[m] = *(const long long*)(pA + (wrow + m * 16 + afr) * 64 + kk * 32 + koff);
#pragma unroll
            for (int n = 0; n < 4; ++n)
                b[n] = *(const long long*)(pB + (wcol + n * 16 + afr) * 64 + kk * 32 + koff);
#pragma unroll
            for (int m = 0; m < 4; ++m)
#pragma unroll
                for (int n = 0; n < 4; ++n)
                    acc[m][n] = __builtin_amdgcn_mfma_f32_16x16x32_fp8_fp8(
                        a[m], b[n], acc[m][n], 0, 0, 0);
        }
        if (kt + 1 < 32) write_tile(cur ^ 1);
        __syncthreads();
    }
    const int crow = (lane >> 4) << 2, ccol = lane & 15;
#pragma unroll
    for (int m = 0; m < 4; ++m)
#pragma unroll
        for (int n = 0; n < 4; ++n) {
            const size_t base = (size_t)(rowBase + wrow + m * 16 + crow) * N_DIM
                              + (colBase + wcol + n * 16 + ccol);
#pragma unroll
            for (int r = 0; r < 4; ++r)
                out[base + (size_t)r * N_DIM] = acc[m][n][r] * sc;
        }
}

extern "C" void kernel_launch(void* const* d_in, const int* in_sizes, int n_in,
                              void* d_out, int out_size, void* d_ws, size_t ws_size,
                              hipStream_t stream) {
    const float* x      = (const float*)d_in[0];
    const float* w      = (const float*)d_in[1];   // fp8 values stored as f32
    const float* wscale = (const float*)d_in[2];
    const float* iscale = (const float*)d_in[3];
    float*       out    = (float*)d_out;

    const size_t needA = (size_t)M_DIM * K_DIM;    // 33.5 MB fp8 X
    const size_t needW = (size_t)N_DIM * K_DIM;    //  4.2 MB fp8 W

    // Raise dynamic-LDS cap to 144 KB (idempotent; host-side, capture-safe).
    hipError_t e = hipFuncSetAttribute((const void*)gemm_mx_256,
                                       hipFuncAttributeMaxDynamicSharedMemorySize,
                                       3 * SLOT);

    if (e == hipSuccess && ws_size >= needA + needW) {
        uint32_t* xq = (uint32_t*)d_ws;
        uint32_t* wq = (uint32_t*)((uint8_t*)d_ws + needA);
        quant_xw_kernel<<<3072, 256, 0, stream>>>(x, w, iscale, xq, wq);
        gemm_mx_256<<<G_GM * G_GN, 512, 3 * SLOT, stream>>>(
            (const uint8_t*)xq, (const uint8_t*)wq, wscale, iscale, out);
    } else {
        fused_fp8_gemm<<<2048, 256, 0, stream>>>(x, w, wscale, iscale, out);
    }
}